// Round 8
// baseline (220.620 us; speedup 1.0000x reference)
//
#include <hip/hip_runtime.h>
#include <hip/hip_bf16.h>
#include <math.h>

// VQ quantizer: single-sweep bf16-MFMA prefilter + fp32-chain-exact rescore.
//   Exact semantics (validated r2/r4/r6): dist = fl32(fl32(r2+e2) - 2*fma_chain(x.e)),
//   argmin first-min-wins.
// Online-threshold capture (round 8): block sweeps cols keeping LDS runmin[row]
//   (prefix min over seen cols). Capture c iff s(c) <= runmin + M. Every runmin
//   snapshot >= final gmin, so all c with mfma(c) <= gmin + 2delta are captured
//   (M=6e-4 >= 2delta~3e-4) -> superset of the r6-validated set. Races only raise
//   the threshold -> safe. Expected captures ~26/row (prefix-min Gumbel sum),
//   CAP=64, exact full-scan fallback if cnt>CAP.
// Outputs (float32 flat): [loss | quantized(8192*256) | indices(8192 as float)]

#define NROWS 8192
#define DDIM  256
#define KCW   8192
#define CAP   64
#define MARGIN 6e-4f
#define TILES 32      // col-tiles per block (half sweep: 32*128 = 4096 cols)

typedef __attribute__((ext_vector_type(8))) short short8;
typedef __attribute__((ext_vector_type(4))) float f32x4;
typedef unsigned int u32;

__device__ inline void async_copy16(void* lds_uniform, const void* gsrc) {
  __builtin_amdgcn_global_load_lds(
      (const __attribute__((address_space(1))) u32*)gsrc,
      (__attribute__((address_space(3))) u32*)lds_uniform, 16, 0, 0);
}

__device__ inline unsigned fmap(float f) {
  unsigned b = __float_as_uint(f);
  return (b & 0x80000000u) ? ~b : (b | 0x80000000u);
}
__device__ inline float funmap(unsigned u) {
  unsigned b = (u & 0x80000000u) ? (u & 0x7FFFFFFFu) : ~u;
  return __uint_as_float(b);
}

// Fused: bf16 cast + e2 (f64->f32, cb rows) + cnt init (z rows).
__global__ __launch_bounds__(256) void k_prep_cast(const float* __restrict__ z,
                                                   const float* __restrict__ cb,
                                                   ushort* __restrict__ zb,
                                                   ushort* __restrict__ cbb,
                                                   float* __restrict__ e2f,
                                                   unsigned* __restrict__ cnt) {
  int t = threadIdx.x, w = t >> 6, lane = t & 63;
  int wid = blockIdx.x * 4 + w;           // 0..16383
  bool isCb = wid >= NROWS;
  int row = isCb ? wid - NROWS : wid;
  const float* src = (isCb ? cb : z) + (size_t)row * DDIM + lane * 4;
  float4 v = *reinterpret_cast<const float4*>(src);
  ushort4 o;
  __hip_bfloat16 bx = __float2bfloat16(v.x); o.x = *(ushort*)&bx;
  __hip_bfloat16 by = __float2bfloat16(v.y); o.y = *(ushort*)&by;
  __hip_bfloat16 bz = __float2bfloat16(v.z); o.z = *(ushort*)&bz;
  __hip_bfloat16 bw = __float2bfloat16(v.w); o.w = *(ushort*)&bw;
  ushort* dst = (isCb ? cbb : zb) + (size_t)row * DDIM + lane * 4;
  *reinterpret_cast<ushort4*>(dst) = o;
  if (isCb) {
    double d = (double)v.x * v.x + (double)v.y * v.y + (double)v.z * v.z + (double)v.w * v.w;
#pragma unroll
    for (int off = 1; off < 64; off <<= 1) d += __shfl_xor(d, off);
    if (lane == 0) e2f[row] = (float)d;
  } else {
    if (lane == 0) cnt[row] = 0;
  }
}

// Sweep: block = 32 rows x 4096 cols (64 col-tiles of 128 would be full row; here
// half -> 32 tiles). 4 waves, wave w owns cols [tile*128 + w*32, +32).
// A (32x256 bf16) lives in registers; B tile (128x256 bf16 = 64KB) staged per
// col-tile via global_load_lds with slot-XOR pre-swizzled source (rule #21).
__global__ __launch_bounds__(256, 2) void k_sweep(const ushort* __restrict__ zb,
                                                  const ushort* __restrict__ cbb,
                                                  const float* __restrict__ e2f,
                                                  unsigned* __restrict__ cnt,
                                                  int* __restrict__ cand) {
  __shared__ ushort Bb[128 * 256];       // [col][k] bf16, 16B-slot swizzled
  __shared__ unsigned runmin[32];
  int t = threadIdx.x, w = t >> 6, lane = t & 63;
  int wg = ((blockIdx.x & 7) << 6) | (blockIdx.x >> 3);   // XCD swizzle (512%8==0)
  int rt = wg >> 1, h = wg & 1;
  int R0 = rt * 32;
  int C0 = h * 4096;
  int cl = lane & 15, g = lane >> 4;

  if (t < 32) runmin[t] = ~0u;

  // A preload: lane holds A[m*16+cl][kk*32 + g*8 .. +8] for m<2, kk<8 (64 VGPR)
  short8 Areg[2][8];
#pragma unroll
  for (int m = 0; m < 2; ++m)
#pragma unroll
    for (int kk = 0; kk < 8; ++kk)
      Areg[m][kk] = *reinterpret_cast<const short8*>(
          &zb[(size_t)(R0 + m * 16 + cl) * DDIM + kk * 32 + g * 8]);
  __syncthreads();                        // runmin init visible

  for (int tile = 0; tile < TILES; ++tile) {
    int CT = C0 + tile * 128;
    // stage B: 4096 granules of 16B; granule gid = i*256 + w*64 + lane
    //   col = gid>>5, slot = gid&31; source slot pre-swizzled: slot ^ (col&7)
#pragma unroll
    for (int i = 0; i < 16; ++i) {
      int col = i * 8 + w * 2 + (lane >> 5);
      const ushort* src = cbb + (size_t)(CT + col) * DDIM + ((lane & 31) ^ (col & 7)) * 8;
      char* dst = (char*)Bb + i * 4096 + w * 1024;   // + lane*16 by hardware
      async_copy16(dst, src);
    }
    float e2v[2];
#pragma unroll
    for (int n = 0; n < 2; ++n) e2v[n] = e2f[CT + w * 32 + n * 16 + cl];
    __syncthreads();                      // drains vmcnt (compiler)

    f32x4 acc[2][2];
#pragma unroll
    for (int m = 0; m < 2; ++m)
#pragma unroll
      for (int n = 0; n < 2; ++n) acc[m][n] = (f32x4){0.f, 0.f, 0.f, 0.f};
#pragma unroll
    for (int kk = 0; kk < 8; ++kk) {
      short8 bfrag[2];
#pragma unroll
      for (int n = 0; n < 2; ++n) {
        int col = w * 32 + n * 16 + cl;
        int addr = col * 512 + (((kk * 4 + g) ^ (col & 7)) << 4);
        bfrag[n] = *reinterpret_cast<const short8*>((char*)Bb + addr);
      }
#pragma unroll
      for (int m = 0; m < 2; ++m)
#pragma unroll
        for (int n = 0; n < 2; ++n)
          acc[m][n] = __builtin_amdgcn_mfma_f32_16x16x32_bf16(Areg[m][kk], bfrag[n], acc[m][n], 0, 0, 0);
    }

    // epilogue: scores; C/D layout col=lane&15, row=(lane>>4)*4+j [m89/m91]
    float sc[2][2][4];
#pragma unroll
    for (int m = 0; m < 2; ++m)
#pragma unroll
      for (int n = 0; n < 2; ++n)
#pragma unroll
        for (int j = 0; j < 4; ++j)
          sc[m][n][j] = __fsub_rn(e2v[n], __fmul_rn(2.0f, acc[m][n][j]));

    // runmin update: per (m,j) reduce over n and the 16 cl-lanes, LDS atomicMin
#pragma unroll
    for (int m = 0; m < 2; ++m)
#pragma unroll
      for (int j = 0; j < 4; ++j) {
        float mn = fminf(sc[m][0][j], sc[m][1][j]);
#pragma unroll
        for (int off = 1; off < 16; off <<= 1) mn = fminf(mn, __shfl_xor(mn, off));
        if (cl == 0) atomicMin(&runmin[m * 16 + g * 4 + j], fmap(mn));
      }
    // capture: threshold from runmin (incl. own tile; staleness is safe)
#pragma unroll
    for (int m = 0; m < 2; ++m)
#pragma unroll
      for (int j = 0; j < 4; ++j) {
        int rloc = m * 16 + g * 4 + j;
        float thr = funmap(runmin[rloc]) + MARGIN;
#pragma unroll
        for (int n = 0; n < 2; ++n) {
          if (sc[m][n][j] <= thr) {
            int row = R0 + rloc;
            unsigned slot = atomicAdd(&cnt[row], 1u);
            if (slot < CAP) cand[row * CAP + slot] = CT + w * 32 + n * 16 + cl;
          }
        }
      }
    __syncthreads();                      // Bb reused next tile
  }
}

// Fused: exact fp32-chain rescore (lex (s,idx) min = first-min-wins) + overflow
// full-scan fallback + gather + per-row loss partial. r2 computed inline.
__global__ __launch_bounds__(256) void k_rescore_gather(const float* __restrict__ z,
                                                        const float* __restrict__ cb,
                                                        const float* __restrict__ e2f,
                                                        const unsigned* __restrict__ cnt,
                                                        const int* __restrict__ cand,
                                                        float* __restrict__ out_q,
                                                        float* __restrict__ out_idx,
                                                        float* __restrict__ lpart) {
  int t = threadIdx.x, w = t >> 6, lane = t & 63;
  int row = blockIdx.x * 4 + w;
  const float* xp = z + (size_t)row * DDIM;
  float4 x4 = *reinterpret_cast<const float4*>(xp + lane * 4);
  double rd = (double)x4.x * x4.x + (double)x4.y * x4.y + (double)x4.z * x4.z + (double)x4.w * x4.w;
#pragma unroll
  for (int off = 1; off < 64; off <<= 1) rd += __shfl_xor(rd, off);
  float r2v = (float)rd;                  // same summation as r6's k_prep (validated)

  unsigned n = cnt[row];
  float s = INFINITY; int ci = 0x7fffffff;
  if (n <= CAP) {
    if (lane < (int)n) {
      ci = cand[row * CAP + lane];
      const float* ep = cb + (size_t)ci * DDIM;
      float acc = 0.f;
      for (int k = 0; k < DDIM; ++k) acc = __fmaf_rn(xp[k], ep[k], acc);  // k ascending
      s = __fsub_rn(__fadd_rn(r2v, e2f[ci]), __fmul_rn(2.0f, acc));
    }
  } else {
    for (int base = 0; base < KCW; base += 64) {      // exact full-scan fallback
      int c = base + lane;
      const float* ep = cb + (size_t)c * DDIM;
      float acc = 0.f;
      for (int k = 0; k < DDIM; ++k) acc = __fmaf_rn(xp[k], ep[k], acc);
      float scv = __fsub_rn(__fadd_rn(r2v, e2f[c]), __fmul_rn(2.0f, acc));
      if (scv < s) { s = scv; ci = c; }
    }
  }
#pragma unroll
  for (int off = 1; off < 64; off <<= 1) {            // butterfly: all lanes get min
    float os = __shfl_xor(s, off); int oi = __shfl_xor(ci, off);
    if (os < s || (os == s && oi < ci)) { s = os; ci = oi; }
  }
  if (lane == 0) out_idx[row] = (float)ci;

  float4 q = *reinterpret_cast<const float4*>(cb + (size_t)ci * DDIM + lane * 4);
  float* o = out_q + (size_t)row * DDIM + lane * 4;   // out+1 base: scalar stores
  o[0] = q.x; o[1] = q.y; o[2] = q.z; o[3] = q.w;
  float dx = q.x - x4.x, dy = q.y - x4.y, dz = q.z - x4.z, dw = q.w - x4.w;
  double d = (double)dx * dx + (double)dy * dy + (double)dz * dz + (double)dw * dw;
#pragma unroll
  for (int off = 1; off < 64; off <<= 1) d += __shfl_xor(d, off);
  if (lane == 0) lpart[row] = (float)d;
}

__global__ __launch_bounds__(256) void k_loss(const float* __restrict__ lpart,
                                              float* __restrict__ out0) {
  __shared__ double red[256];
  int t = threadIdx.x;
  double s = 0.0;
  for (int j = t; j < NROWS; j += 256) s += lpart[j];  // fixed order -> deterministic
  red[t] = s;
  __syncthreads();
  for (int off = 128; off > 0; off >>= 1) {
    if (t < off) red[t] += red[t + off];
    __syncthreads();
  }
  if (t == 0) out0[0] = (float)(1.25 * red[0] / (double)((size_t)NROWS * DDIM));
}

extern "C" void kernel_launch(void* const* d_in, const int* in_sizes, int n_in,
                              void* d_out, int out_size, void* d_ws, size_t ws_size,
                              hipStream_t stream) {
  const float* z  = (const float*)d_in[0];   // [16,512,256] flat
  const float* cb = (const float*)d_in[1];   // [8192,256]
  float* out = (float*)d_out;
  char* ws = (char*)d_ws;
  const size_t HALF = (size_t)NROWS * DDIM;  // 2,097,152

  // bf16 copies in the out_q region (out+4 floats: 16B-aligned). Last 3 floats
  // of cbb overlap out_idx[0..2]; out_idx is written by k_rescore_gather, which
  // runs after the last zb/cbb read (k_sweep). Recomputed every call.
  ushort* zb  = (ushort*)(out + 4);
  ushort* cbb = zb + HALF;

  // ws: e2f 32K | cnt 32K | lpart(f32) 32K | cand 8192*64*4 = 2MB
  // total 2,195,456 B  (< 2,211,840 proven working in round 2)
  size_t off = 0;
  float*    e2f   = (float*)(ws + off);    off += NROWS * 4;
  unsigned* cnt   = (unsigned*)(ws + off); off += NROWS * 4;
  float*    lpart = (float*)(ws + off);    off += NROWS * 4;
  int*      cand  = (int*)(ws + off);      off += (size_t)NROWS * CAP * 4;

  float* out_q   = out + 1;
  float* out_idx = out + 1 + HALF;

  k_prep_cast     <<<(2 * NROWS) / 4, 256, 0, stream>>>(z, cb, zb, cbb, e2f, cnt);
  k_sweep         <<<512,             256, 0, stream>>>(zb, cbb, e2f, cnt, cand);
  k_rescore_gather<<<NROWS / 4,       256, 0, stream>>>(z, cb, e2f, cnt, cand, out_q, out_idx, lpart);
  k_loss          <<<1,               256, 0, stream>>>(lpart, out);
}